// Round 11
// baseline (224.232 us; speedup 1.0000x reference)
//
#include <hip/hip_runtime.h>

// KanLinear: out[b,o] = silu(x)@scale_base + bases@(spline_w*scale_spline)
// Round 11: REVERT to the r9 two-launch path (known-good, 219.4us).
// r10's cooperative launch invalidated graph capture (hipLaunchCooperativeKernel
// is capture-incompatible on this harness even with an error-check fallback) --
// treat it as forbidden, like hipMalloc.
// Structure: launch 1 = pure elementwise prep (all streams coalesced);
// launch 2 = unified 2-phase GEMM (fp8 MX K=8192 + bf16 K=1024, shared
// accumulator, plain-store epilogue) at the m148 structure plateau (~95us).

#define BATCH 8192
#define IN_F  1024
#define OUT_F 1024
#define GRID_N 8
#define K2    (IN_F * GRID_N)          // spline K = 8192
#define KTOT  (IN_F + K2)              // 9216 (fallback path)

#define BM 128
#define BN 128
#define BK 64        // bf16 k-tile
#define BK8 128      // fp8 k-tile (bytes)

typedef __bf16 bf16x8 __attribute__((ext_vector_type(8)));
typedef float  f32x4  __attribute__((ext_vector_type(4)));
typedef int    int32x8 __attribute__((ext_vector_type(8)));

__device__ __forceinline__ void gl2lds16(const void* g, void* l) {
  __builtin_amdgcn_global_load_lds(
      (const __attribute__((address_space(1))) void*)g,
      (__attribute__((address_space(3))) void*)l, 16, 0, 0);
}

__device__ __forceinline__ void pack_fp8x8(const float* v, int& w0, int& w1) {
  w0 = 0; w1 = 0;
  w0 = __builtin_amdgcn_cvt_pk_fp8_f32(v[0], v[1], w0, false);
  w0 = __builtin_amdgcn_cvt_pk_fp8_f32(v[2], v[3], w0, true);
  w1 = __builtin_amdgcn_cvt_pk_fp8_f32(v[4], v[5], w1, false);
  w1 = __builtin_amdgcn_cvt_pk_fp8_f32(v[6], v[7], w1, true);
}

// ---------- launch 1: pure elementwise prep, all streams coalesced ----------
// blocks [0,256):      sbT[o][k] = (bf16)scale_base[k][o]  (LDS transpose)
// blocks [256,512):    spline-pack tile 64o x 512j with LDS-staged ss
// blocks [512,8704):   row b: sbA[b][k]=bf16(silu(x)), Ab8[b][i*8+g]=fp8(base)
__global__ __launch_bounds__(256)
void kan_mix(const float* __restrict__ x, const float* __restrict__ sb,
             const float* __restrict__ sw, const float* __restrict__ ss,
             const float* __restrict__ grid, const float* __restrict__ sigma,
             __bf16* __restrict__ sbT, unsigned char* __restrict__ wbt8,
             unsigned char* __restrict__ Ab8, __bf16* __restrict__ sbA) {
  const int t = threadIdx.x;
  const int bx = blockIdx.x;
  if (bx < 256) {
    // ---- sb transpose (64x64 f32 tiles) ----
    __shared__ float tile[64][65];
    const int o0 = (bx & 15) * 64, k0 = (bx >> 4) * 64;
    const int r = t >> 4, c4 = (t & 15) * 4;
    #pragma unroll
    for (int it = 0; it < 4; ++it) {
      const int k = k0 + r + it * 16;
      float4 v = *(const float4*)(sb + (size_t)k * OUT_F + o0 + c4);
      tile[r + it * 16][c4 + 0] = v.x; tile[r + it * 16][c4 + 1] = v.y;
      tile[r + it * 16][c4 + 2] = v.z; tile[r + it * 16][c4 + 3] = v.w;
    }
    __syncthreads();
    #pragma unroll
    for (int it = 0; it < 4; ++it) {
      const int ol = r + it * 16;
      union { __bf16 h[4]; uint2 q; } s;
      #pragma unroll
      for (int e = 0; e < 4; ++e) s.h[e] = (__bf16)tile[c4 + e][ol];
      *(uint2*)(sbT + (size_t)(o0 + ol) * IN_F + k0 + c4) = s.q;
    }
  } else if (bx < 512) {
    // ---- spline-pack: tile = o in [o0,o0+64), j in [j0,j0+512), i=j/8 ----
    __shared__ float tile[64][65];        // tile[i_local][o_local]
    const int sp = bx - 256;              // [0,256)
    const int o0 = (sp >> 4) * 64;
    const int j0 = (sp & 15) * 512;
    const int i0 = j0 >> 3;               // 64 i's per tile
    const int r = t >> 4, c4 = (t & 15) * 4;
    #pragma unroll
    for (int it = 0; it < 4; ++it) {
      const int i = i0 + r + it * 16;
      float4 v = *(const float4*)(ss + (size_t)i * OUT_F + o0 + c4);
      tile[r + it * 16][c4 + 0] = v.x; tile[r + it * 16][c4 + 1] = v.y;
      tile[r + it * 16][c4 + 2] = v.z; tile[r + it * 16][c4 + 3] = v.w;
    }
    __syncthreads();
    #pragma unroll
    for (int p = 0; p < 16; ++p) {
      const int f = p * 256 + t;
      const int o_l = f >> 6, i_l = f & 63;
      const float sc = tile[i_l][o_l];
      const float* swp = sw + (size_t)(o0 + o_l) * K2 + j0 + i_l * 8;
      float4 a = *(const float4*)swp;
      float4 b = *(const float4*)(swp + 4);
      float vv[8] = {a.x * sc, a.y * sc, a.z * sc, a.w * sc,
                     b.x * sc, b.y * sc, b.z * sc, b.w * sc};
      int w0, w1; pack_fp8x8(vv, w0, w1);
      *(int2*)(wbt8 + (size_t)(o0 + o_l) * K2 + j0 + i_l * 8) = make_int2(w0, w1);
    }
  } else {
    // ---- per-row x prep: silu (bf16) + RBF bases (fp8) ----
    const int b = bx - 512;
    const float inv_sigma = 1.0f / sigma[0];
    const float* xrow = x + (size_t)b * IN_F;
    unsigned char* arow = Ab8 + (size_t)b * K2;
    __bf16* srow = sbA + (size_t)b * IN_F;
    {
      float4 v = ((const float4*)xrow)[t];
      float vv[4] = {v.x, v.y, v.z, v.w};
      union { __bf16 h[4]; uint2 q; } s;
      #pragma unroll
      for (int e = 0; e < 4; ++e) s.h[e] = (__bf16)(vv[e] / (1.0f + __expf(-vv[e])));
      ((uint2*)srow)[t] = s.q;
    }
    #pragma unroll
    for (int it = 0; it < 4; ++it) {
      const int i = t + it * 256;
      const float u = xrow[i];
      float4 g0 = *(const float4*)(grid + (size_t)i * GRID_N);
      float4 g1 = *(const float4*)(grid + (size_t)i * GRID_N + 4);
      float gg[8] = {g0.x, g0.y, g0.z, g0.w, g1.x, g1.y, g1.z, g1.w};
      float bb[8];
      #pragma unroll
      for (int g = 0; g < GRID_N; ++g) {
        float d = (u - gg[g]) * inv_sigma;
        bb[g] = __expf(-d * d);
      }
      int w0, w1; pack_fp8x8(bb, w0, w1);
      *(int2*)(arow + (size_t)i * GRID_N) = make_int2(w0, w1);
    }
  }
}

// ---------- launch 2: unified GEMM, fp8 phase (K=8192) + bf16 phase (K=1024) ----------
__global__ __launch_bounds__(256)
void kan_gemm_all(const unsigned char* __restrict__ Ab8,
                  const unsigned char* __restrict__ wbt8,
                  const __bf16* __restrict__ sbA,
                  const __bf16* __restrict__ sbT,
                  float* __restrict__ out) {
  __shared__ unsigned char As8[BM * BK8];   // 16 KB; bf16 phase aliases it
  __shared__ unsigned char Bs8[BN * BK8];   // 16 KB
  __bf16* As16 = (__bf16*)As8;
  __bf16* Bs16 = (__bf16*)Bs8;

  const int tid = threadIdx.x;
  const int bx  = blockIdx.x;
  const int s   = bx >> 3;
  const int r0  = ((bx & 7) * 8 + (s >> 3)) * BM;
  const int c0  = (s & 7) * BN;

  const int lane = tid & 63, wave = tid >> 6;
  const int wm = wave & 1, wn = wave >> 1;
  const int quad = lane >> 4, l15 = lane & 15;

  int a_off8[4][2], b_off8[4][2];
  #pragma unroll
  for (int t4 = 0; t4 < 4; ++t4) {
    const int rowA = wm * 64 + t4 * 16 + l15;
    const int rowB = wn * 64 + t4 * 16 + l15;
    #pragma unroll
    for (int h = 0; h < 2; ++h) {
      a_off8[t4][h] = rowA * BK8 + (((quad * 2 + h) ^ (rowA & 7)) * 16);
      b_off8[t4][h] = rowB * BK8 + (((quad * 2 + h) ^ (rowB & 7)) * 16);
    }
  }
  int a_off16[2][4], b_off16[2][4];
  #pragma unroll
  for (int ks = 0; ks < 2; ++ks) {
    const int kc = ks * 4 + quad;
    #pragma unroll
    for (int t4 = 0; t4 < 4; ++t4) {
      const int rowA = wm * 64 + t4 * 16 + l15;
      a_off16[ks][t4] = (rowA * 8 + (kc ^ (rowA & 7))) * 8;
      const int rowB = wn * 64 + t4 * 16 + l15;
      b_off16[ks][t4] = (rowB * 8 + (kc ^ (rowB & 7))) * 8;
    }
  }
  const unsigned char* aSrc8[4]; const unsigned char* bSrc8[4];
  const __bf16* aSrc16[4]; const __bf16* bSrc16[4]; int dstOff[4];
  #pragma unroll
  for (int it = 0; it < 4; ++it) {
    const int p = it * 256 + tid;
    const int row = p >> 3;
    const int kc  = (p & 7) ^ (row & 7);
    aSrc8[it]  = Ab8  + (size_t)(r0 + row) * K2 + kc * 16;
    bSrc8[it]  = wbt8 + (size_t)(c0 + row) * K2 + kc * 16;
    aSrc16[it] = sbA  + (size_t)(r0 + row) * IN_F + kc * 8;
    bSrc16[it] = sbT  + (size_t)(c0 + row) * IN_F + kc * 8;
    dstOff[it] = p * 16;
  }

  f32x4 zero; zero[0] = 0.f; zero[1] = 0.f; zero[2] = 0.f; zero[3] = 0.f;
  f32x4 acc[4][4];
  #pragma unroll
  for (int a = 0; a < 4; ++a)
    #pragma unroll
    for (int b = 0; b < 4; ++b) acc[a][b] = zero;

  // ---- phase 1: fp8 MX spline, 64 iters ----
  for (int kb = 0; kb < K2; kb += BK8) {
    __syncthreads();
    #pragma unroll
    for (int it = 0; it < 4; ++it) {
      gl2lds16(aSrc8[it] + kb, &As8[dstOff[it]]);
      gl2lds16(bSrc8[it] + kb, &Bs8[dstOff[it]]);
    }
    __syncthreads();
    union frag { int32x8 v; uint4 q[2]; };
    frag af[4], bfv[4];
    #pragma unroll
    for (int t4 = 0; t4 < 4; ++t4) {
      af[t4].q[0]  = *(const uint4*)&As8[a_off8[t4][0]];
      af[t4].q[1]  = *(const uint4*)&As8[a_off8[t4][1]];
      bfv[t4].q[0] = *(const uint4*)&Bs8[b_off8[t4][0]];
      bfv[t4].q[1] = *(const uint4*)&Bs8[b_off8[t4][1]];
    }
    #pragma unroll
    for (int tm = 0; tm < 4; ++tm)
      #pragma unroll
      for (int tn = 0; tn < 4; ++tn)
        acc[tm][tn] = __builtin_amdgcn_mfma_scale_f32_16x16x128_f8f6f4(
            af[tm].v, bfv[tn].v, acc[tm][tn],
            0, 0, 0, 0x7F7F7F7F, 0, 0x7F7F7F7F);
  }

  // ---- phase 2: bf16 base, 16 iters (same acc) ----
  for (int kb = 0; kb < IN_F; kb += BK) {
    __syncthreads();
    #pragma unroll
    for (int it = 0; it < 4; ++it) {
      gl2lds16(aSrc16[it] + kb, (char*)As16 + dstOff[it]);
      gl2lds16(bSrc16[it] + kb, (char*)Bs16 + dstOff[it]);
    }
    __syncthreads();
    #pragma unroll
    for (int ks = 0; ks < 2; ++ks) {
      bf16x8 af[4], bfv[4];
      #pragma unroll
      for (int t4 = 0; t4 < 4; ++t4) af[t4]  = *(const bf16x8*)&As16[a_off16[ks][t4]];
      #pragma unroll
      for (int t4 = 0; t4 < 4; ++t4) bfv[t4] = *(const bf16x8*)&Bs16[b_off16[ks][t4]];
      #pragma unroll
      for (int tm = 0; tm < 4; ++tm)
        #pragma unroll
        for (int tn = 0; tn < 4; ++tn)
          acc[tm][tn] = __builtin_amdgcn_mfma_f32_16x16x32_bf16(
              af[tm], bfv[tn], acc[tm][tn], 0, 0, 0);
    }
  }

  // ---- epilogue: plain store ----
  #pragma unroll
  for (int tm = 0; tm < 4; ++tm) {
    const int row = r0 + wm * 64 + tm * 16 + quad * 4;
    #pragma unroll
    for (int tn = 0; tn < 4; ++tn) {
      const int col = c0 + wn * 64 + tn * 16 + l15;
      float* op = out + (size_t)row * OUT_F + col;
      #pragma unroll
      for (int r = 0; r < 4; ++r)
        op[(size_t)r * OUT_F] = acc[tm][tn][r];
    }
  }
}

// ---------- fallback path (ws too small): full-W bf16 prep + fused gemm ----------
__global__ __launch_bounds__(256)
void kan_prep_w_full(const float* __restrict__ sb, const float* __restrict__ sw,
                     const float* __restrict__ ss, __bf16* __restrict__ wbt) {
  const int t = threadIdx.x;
  if (blockIdx.x < 256) {
    __shared__ float tile[64][65];
    const int o0 = (blockIdx.x & 15) * 64, k0 = (blockIdx.x >> 4) * 64;
    const int r = t >> 4, c4 = (t & 15) * 4;
    #pragma unroll
    for (int it = 0; it < 4; ++it) {
      const int k = k0 + r + it * 16;
      float4 v = *(const float4*)(sb + (size_t)k * OUT_F + o0 + c4);
      tile[r + it * 16][c4 + 0] = v.x; tile[r + it * 16][c4 + 1] = v.y;
      tile[r + it * 16][c4 + 2] = v.z; tile[r + it * 16][c4 + 3] = v.w;
    }
    __syncthreads();
    #pragma unroll
    for (int it = 0; it < 4; ++it) {
      const int ol = r + it * 16;
      union { __bf16 h[4]; uint2 q; } s;
      #pragma unroll
      for (int e = 0; e < 4; ++e) s.h[e] = (__bf16)tile[c4 + e][ol];
      *(uint2*)(wbt + (size_t)(o0 + ol) * KTOT + k0 + c4) = s.q;
    }
  } else {
    const size_t e = ((size_t)(blockIdx.x - 256) * 256 + t) * 8;
    const int o = (int)(e >> 13);
    const int j = (int)(e & 8191);
    const int i = j >> 3;
    const float sc = ss[(size_t)i * OUT_F + o];
    float4 a = *(const float4*)(sw + e);
    float4 b = *(const float4*)(sw + e + 4);
    float vv[8] = {a.x, a.y, a.z, a.w, b.x, b.y, b.z, b.w};
    union { __bf16 h[8]; uint4 q; } s;
    #pragma unroll
    for (int g = 0; g < 8; ++g) s.h[g] = (__bf16)(vv[g] * sc);
    *(uint4*)(wbt + (size_t)o * KTOT + IN_F + j) = s.q;
  }
}

__global__ __launch_bounds__(256, 2)
void kan_gemm_fused(const float* __restrict__ x, const __bf16* __restrict__ wbt,
                    const float* __restrict__ grid, const float* __restrict__ sigma,
                    float* __restrict__ out) {
  __shared__ __bf16 As[BM * BK];
  __shared__ __bf16 Bs[BN * BK];
  __shared__ float  gLds[IN_F * GRID_N];
  const int tid = threadIdx.x;
  const int bx  = blockIdx.x;
  const int c0  = (bx & 7) * BN;
  const int r0  = (bx >> 3) * BM;
  for (int idx = tid; idx < IN_F * GRID_N / 4; idx += 256)
    ((float4*)gLds)[idx] = ((const float4*)grid)[idx];
  const float inv_sigma = 1.0f / sigma[0];
  const int lane = tid & 63, wave = tid >> 6;
  const int wm = wave & 1, wn = wave >> 1;
  const int quad = lane >> 4, l15 = lane & 15;
  f32x4 zero; zero[0] = 0.f; zero[1] = 0.f; zero[2] = 0.f; zero[3] = 0.f;
  f32x4 acc[4][4];
  #pragma unroll
  for (int a = 0; a < 4; ++a)
    #pragma unroll
    for (int b = 0; b < 4; ++b) acc[a][b] = zero;
  const int m = tid >> 1, half = tid & 1;
  const float* xrow = x + (size_t)(r0 + m) * IN_F;
  __syncthreads();
  for (int kb = 0; kb < KTOT; kb += BK) {
    union { __bf16 h[32]; uint4 q[4]; } av;
    if (kb < IN_F) {
      const float4* xp = (const float4*)(xrow + kb + half * 32);
      #pragma unroll
      for (int j4 = 0; j4 < 8; ++j4) {
        float4 v = xp[j4];
        float vv[4] = {v.x, v.y, v.z, v.w};
        #pragma unroll
        for (int e = 0; e < 4; ++e)
          av.h[j4 * 4 + e] = (__bf16)(vv[e] / (1.0f + __expf(-vv[e])));
      }
    } else {
      const int i0 = (kb - IN_F) >> 3;
      float4 xv = *(const float4*)(xrow + i0 + half * 4);
      float xs[4] = {xv.x, xv.y, xv.z, xv.w};
      #pragma unroll
      for (int ii = 0; ii < 4; ++ii) {
        const float u = xs[ii];
        const float* gp = &gLds[(i0 + half * 4 + ii) * GRID_N];
        #pragma unroll
        for (int g = 0; g < GRID_N; ++g) {
          float d = (u - gp[g]) * inv_sigma;
          av.h[ii * 8 + g] = (__bf16)__expf(-d * d);
        }
      }
    }
    __syncthreads();
    {
      uint4* dst = (uint4*)&As[m * BK + half * 32];
      #pragma unroll
      for (int qd = 0; qd < 4; ++qd) dst[qd] = av.q[qd];
    }
    #pragma unroll
    for (int it = 0; it < 4; ++it) {
      const int idx = it * 2048 + tid * 8;
      const int n = idx >> 6, k = idx & 63;
      gl2lds16(wbt + (size_t)(c0 + n) * KTOT + kb + k, &Bs[idx]);
    }
    __syncthreads();
    #pragma unroll
    for (int ks = 0; ks < 2; ++ks) {
      bf16x8 af[4], bfv[4];
      #pragma unroll
      for (int t4 = 0; t4 < 4; ++t4)
        af[t4] = *(const bf16x8*)&As[(wm * 64 + t4 * 16 + l15) * BK + ks * 32 + quad * 8];
      #pragma unroll
      for (int t4 = 0; t4 < 4; ++t4)
        bfv[t4] = *(const bf16x8*)&Bs[(wn * 64 + t4 * 16 + l15) * BK + ks * 32 + quad * 8];
      #pragma unroll
      for (int tm = 0; tm < 4; ++tm)
        #pragma unroll
        for (int tn = 0; tn < 4; ++tn)
          acc[tm][tn] = __builtin_amdgcn_mfma_f32_16x16x32_bf16(
              af[tm], bfv[tn], acc[tm][tn], 0, 0, 0);
    }
  }
  #pragma unroll
  for (int tm = 0; tm < 4; ++tm) {
    const int row = r0 + wm * 64 + tm * 16 + quad * 4;
    #pragma unroll
    for (int tn = 0; tn < 4; ++tn) {
      const int col = c0 + wn * 64 + tn * 16 + l15;
      float* op = out + (size_t)row * OUT_F + col;
      #pragma unroll
      for (int r = 0; r < 4; ++r)
        op[(size_t)r * OUT_F] = acc[tm][tn][r];
    }
  }
}

extern "C" void kernel_launch(void* const* d_in, const int* in_sizes, int n_in,
                              void* d_out, int out_size, void* d_ws, size_t ws_size,
                              hipStream_t stream) {
  const float* x     = (const float*)d_in[0];
  const float* sb    = (const float*)d_in[1];
  const float* sw    = (const float*)d_in[2];
  const float* ss    = (const float*)d_in[3];
  const float* grid  = (const float*)d_in[4];
  const float* sigma = (const float*)d_in[5];
  float* out = (float*)d_out;

  const size_t SBT_BYTES = (size_t)OUT_F * IN_F * 2;   //   2 MB (bf16)
  const size_t WS_BYTES  = (size_t)OUT_F * K2;         //  8.4 MB (fp8)
  const size_t A_BYTES   = (size_t)BATCH * K2;         // 67.1 MB (fp8)
  const size_t SBA_BYTES = (size_t)BATCH * IN_F * 2;   // 16.8 MB (bf16)

  if (ws_size >= SBT_BYTES + WS_BYTES + A_BYTES + SBA_BYTES) {
    __bf16*        sbT  = (__bf16*)d_ws;
    unsigned char* wbt8 = (unsigned char*)d_ws + SBT_BYTES;
    unsigned char* Ab8  = (unsigned char*)d_ws + SBT_BYTES + WS_BYTES;
    __bf16*        sbA  = (__bf16*)((char*)d_ws + SBT_BYTES + WS_BYTES + A_BYTES);
    kan_mix<<<dim3(512 + BATCH), dim3(256), 0, stream>>>(
        x, sb, sw, ss, grid, sigma, sbT, wbt8, Ab8, sbA);
    kan_gemm_all<<<dim3((BATCH / BM) * (OUT_F / BN)), dim3(256), 0, stream>>>(
        Ab8, wbt8, sbA, sbT, out);
  } else {
    __bf16* wbt = (__bf16*)d_ws;   // 18.9 MB
    kan_prep_w_full<<<dim3(4352), dim3(256), 0, stream>>>(sb, sw, ss, wbt);
    kan_gemm_fused<<<dim3((BATCH / BM) * (OUT_F / BN)), dim3(256), 0, stream>>>(
        x, wbt, grid, sigma, out);
  }
}